// Round 1
// baseline (415.942 us; speedup 1.0000x reference)
//
#include <hip/hip_runtime.h>
#include <math.h>

#define HW_ (1024*1024)

// ---------------- generic direct 3x3 conv (NCHW, OIHW) ----------------
template<int CIN, int S, bool RELU>
__global__ void conv3x3(const float* __restrict__ in, const float* __restrict__ w,
                        const float* __restrict__ bias, float* __restrict__ out,
                        int B, int COUT, int HIN, int WIN, int HOUT, int WOUT)
{
    int idx = blockIdx.x * blockDim.x + threadIdx.x;
    int total = B * COUT * HOUT * WOUT;
    if (idx >= total) return;
    int wo = idx % WOUT; int t = idx / WOUT;
    int ho = t % HOUT; t /= HOUT;
    int co = t % COUT; int b = t / COUT;

    float acc = bias[co];
    const float* wp = w + co * CIN * 9;
    const float* ip = in + (size_t)b * CIN * HIN * WIN;
    for (int ci = 0; ci < CIN; ci++) {
        #pragma unroll
        for (int kh = 0; kh < 3; kh++) {
            int hi = ho * S - 1 + kh;
            if (hi < 0 || hi >= HIN) continue;
            #pragma unroll
            for (int kw = 0; kw < 3; kw++) {
                int wi = wo * S - 1 + kw;
                if (wi < 0 || wi >= WIN) continue;
                acc += ip[(ci * HIN + hi) * WIN + wi] * wp[(ci * 3 + kh) * 3 + kw];
            }
        }
    }
    if (RELU) acc = fmaxf(acc, 0.f);
    out[idx] = acc;
}

// ---------------- FC head: [B,1024] -> 256 -> 128 -> 64 ----------------
__global__ void fc_head(const float* __restrict__ g1, const float* __restrict__ w0,
                        const float* __restrict__ b0, const float* __restrict__ w1,
                        const float* __restrict__ b1, const float* __restrict__ w2,
                        const float* __restrict__ b2, float* __restrict__ gvec)
{
    __shared__ float v[1024];
    __shared__ float h0[256];
    __shared__ float h1[128];
    int b = blockIdx.x;
    int t = threadIdx.x; // 256 threads
    for (int i = t; i < 1024; i += 256) v[i] = g1[b * 1024 + i];
    __syncthreads();
    {
        float acc = b0[t];
        const float* wr = w0 + t * 1024;
        for (int k = 0; k < 1024; k++) acc += wr[k] * v[k];
        h0[t] = fmaxf(acc, 0.f);
    }
    __syncthreads();
    if (t < 128) {
        float acc = b1[t];
        const float* wr = w1 + t * 256;
        for (int k = 0; k < 256; k++) acc += wr[k] * h0[k];
        h1[t] = fmaxf(acc, 0.f);
    }
    __syncthreads();
    if (t < 64) {
        float acc = b2[t];
        const float* wr = w2 + t * 128;
        for (int k = 0; k < 128; k++) acc += wr[k] * h1[k];
        gvec[b * 64 + t] = acc;
    }
}

// ------- fusion (loc + g broadcast, relu) + 1x1 bg conv -> grid[B,8,16,16,12] -------
__global__ void fuse_bg(const float* __restrict__ loc, const float* __restrict__ gvec,
                        const float* __restrict__ bgw, const float* __restrict__ bgb,
                        float* __restrict__ grid_r)
{
    __shared__ float fused[64];
    int b = blockIdx.y;
    int y = blockIdx.x >> 4, x = blockIdx.x & 15;
    int t = threadIdx.x; // 128 threads
    if (t < 64) {
        fused[t] = fmaxf(loc[((b * 64 + t) * 16 + y) * 16 + x] + gvec[b * 64 + t], 0.f);
    }
    __syncthreads();
    if (t < 96) {
        float acc = bgb[t];
        const float* wr = bgw + t * 64;
        #pragma unroll 8
        for (int k = 0; k < 64; k++) acc += wr[k] * fused[k];
        // bg channel t -> (c12 = t/8, d = t%8); store [b][d][y][x][c12]
        int c12 = t >> 3, d = t & 7;
        grid_r[((((b * 8 + d) * 16 + y) * 16 + x) * 12) + c12] = acc;
    }
}

// ------- fused guide (1x1 convs + sigmoid) + trilinear slice + affine apply -------
__global__ void guide_slice(const float* __restrict__ fr, const float* __restrict__ grid_r,
                            const float* __restrict__ guw0, const float* __restrict__ gub0,
                            const float* __restrict__ guw1, const float* __restrict__ gub1,
                            float* __restrict__ gd_out, float* __restrict__ fin_out)
{
    const int W = 1024;
    int x = blockIdx.x * 64 + (threadIdx.x & 63);
    int y = blockIdx.y * 4 + (threadIdx.x >> 6);
    int b = blockIdx.z;
    int pix = y * W + x;

    const float* frb = fr + (size_t)b * 3 * HW_;
    float r  = frb[pix];
    float g  = frb[HW_ + pix];
    float bl = frb[2 * HW_ + pix];

    // guide network: 3 -> 16 (relu) -> 1 (sigmoid)
    float s = gub1[0];
    #pragma unroll
    for (int c = 0; c < 16; c++) {
        float h = guw0[c * 3] * r + guw0[c * 3 + 1] * g + guw0[c * 3 + 2] * bl + gub0[c];
        h = fmaxf(h, 0.f);
        s += guw1[c] * h;
    }
    float gd = 1.f / (1.f + expf(-s));
    gd_out[(size_t)b * HW_ + pix] = gd;

    // slice coordinates
    float xs = (x + 0.5f) * (1.f / 64.f) - 0.5f;
    float ys = (y + 0.5f) * (1.f / 64.f) - 0.5f;
    float fx = floorf(xs), fy = floorf(ys);
    int x0 = min(max((int)fx, 0), 15); int x1 = min(x0 + 1, 15);
    int y0 = min(max((int)fy, 0), 15); int y1 = min(y0 + 1, 15);
    float wx = xs - fx, wy = ys - fy;

    float gz = gd * 8.f - 0.5f;
    float fz = floorf(gz);
    int z0 = min(max((int)fz, 0), 7); int z1 = min(z0 + 1, 7);
    float wz = gz - fz;

    float acc[12];
    #pragma unroll
    for (int c = 0; c < 12; c++) acc[c] = 0.f;

    const float* gb = grid_r + (size_t)b * 8 * 16 * 16 * 12;
    #pragma unroll
    for (int zi = 0; zi < 2; zi++) {
        int z = zi ? z1 : z0;
        float wzf = zi ? wz : 1.f - wz;
        #pragma unroll
        for (int yi = 0; yi < 2; yi++) {
            int yy = yi ? y1 : y0;
            float wyf = wzf * (yi ? wy : 1.f - wy);
            #pragma unroll
            for (int xi = 0; xi < 2; xi++) {
                int xx = xi ? x1 : x0;
                float wf = wyf * (xi ? wx : 1.f - wx);
                const float4* p = (const float4*)(gb + ((z * 16 + yy) * 16 + xx) * 12);
                float4 a0 = p[0], a1 = p[1], a2 = p[2];
                acc[0] += wf * a0.x; acc[1]  += wf * a0.y; acc[2]  += wf * a0.z; acc[3]  += wf * a0.w;
                acc[4] += wf * a1.x; acc[5]  += wf * a1.y; acc[6]  += wf * a1.z; acc[7]  += wf * a1.w;
                acc[8] += wf * a2.x; acc[9]  += wf * a2.y; acc[10] += wf * a2.z; acc[11] += wf * a2.w;
            }
        }
    }

    float o0 = acc[0] * r + acc[1] * g + acc[2]  * bl + acc[3];
    float o1 = acc[4] * r + acc[5] * g + acc[6]  * bl + acc[7];
    float o2 = acc[8] * r + acc[9] * g + acc[10] * bl + acc[11];
    float* fb = fin_out + (size_t)b * 3 * HW_;
    fb[pix] = o0; fb[HW_ + pix] = o1; fb[2 * HW_ + pix] = o2;
}

extern "C" void kernel_launch(void* const* d_in, const int* in_sizes, int n_in,
                              void* d_out, int out_size, void* d_ws, size_t ws_size,
                              hipStream_t stream) {
    const float* lr   = (const float*)d_in[0];
    const float* fr   = (const float*)d_in[1];
    const float* sw0  = (const float*)d_in[2];  const float* sb0 = (const float*)d_in[3];
    const float* sw1  = (const float*)d_in[4];  const float* sb1 = (const float*)d_in[5];
    const float* sw2  = (const float*)d_in[6];  const float* sb2 = (const float*)d_in[7];
    const float* sw3  = (const float*)d_in[8];  const float* sb3 = (const float*)d_in[9];
    const float* lw0  = (const float*)d_in[10]; const float* lb0 = (const float*)d_in[11];
    const float* lw1  = (const float*)d_in[12]; const float* lb1 = (const float*)d_in[13];
    const float* gcw0 = (const float*)d_in[14]; const float* gcb0 = (const float*)d_in[15];
    const float* gcw1 = (const float*)d_in[16]; const float* gcb1 = (const float*)d_in[17];
    const float* fcw0 = (const float*)d_in[18]; const float* fcb0 = (const float*)d_in[19];
    const float* fcw1 = (const float*)d_in[20]; const float* fcb1 = (const float*)d_in[21];
    const float* fcw2 = (const float*)d_in[22]; const float* fcb2 = (const float*)d_in[23];
    const float* bgw  = (const float*)d_in[24]; const float* bgb = (const float*)d_in[25];
    const float* guw0 = (const float*)d_in[26]; const float* gub0 = (const float*)d_in[27];
    const float* guw1 = (const float*)d_in[28]; const float* gub1 = (const float*)d_in[29];

    float* ws = (float*)d_ws;
    float* ws0    = ws;            // [2,8,128,128]  262144
    float* ws1    = ws + 262144;   // [2,16,64,64]   131072
    float* ws2    = ws + 393216;   // [2,32,32,32]   65536
    float* ws3    = ws + 458752;   // [2,64,16,16]   32768
    float* loc0   = ws + 491520;   // [2,64,16,16]   32768
    float* loc    = ws + 524288;   // [2,64,16,16]   32768
    float* g0     = ws + 557056;   // [2,64,8,8]     8192
    float* g1     = ws + 565248;   // [2,64,4,4]     2048
    float* gvec   = ws + 567296;   // [2,64]         128
    float* grid_r = ws + 567424;   // [2,8,16,16,12] 49152

    float* gd_out  = (float*)d_out;             // [2,1024,1024]
    float* fin_out = (float*)d_out + 2 * HW_;   // [2,3,1024,1024]

    const int B = 2;

    // splat stack
    conv3x3<3, 2, true><<<dim3((B*8*128*128 + 255) / 256), 256, 0, stream>>>(
        lr, sw0, sb0, ws0, B, 8, 256, 256, 128, 128);
    conv3x3<8, 2, true><<<dim3((B*16*64*64 + 255) / 256), 256, 0, stream>>>(
        ws0, sw1, sb1, ws1, B, 16, 128, 128, 64, 64);
    conv3x3<16, 2, true><<<dim3((B*32*32*32 + 255) / 256), 256, 0, stream>>>(
        ws1, sw2, sb2, ws2, B, 32, 64, 64, 32, 32);
    conv3x3<32, 2, true><<<dim3((B*64*16*16 + 255) / 256), 256, 0, stream>>>(
        ws2, sw3, sb3, ws3, B, 64, 32, 32, 16, 16);

    // local path
    conv3x3<64, 1, true><<<dim3((B*64*16*16 + 255) / 256), 256, 0, stream>>>(
        ws3, lw0, lb0, loc0, B, 64, 16, 16, 16, 16);
    conv3x3<64, 1, false><<<dim3((B*64*16*16 + 255) / 256), 256, 0, stream>>>(
        loc0, lw1, lb1, loc, B, 64, 16, 16, 16, 16);

    // global path
    conv3x3<64, 2, true><<<dim3((B*64*8*8 + 255) / 256), 256, 0, stream>>>(
        ws3, gcw0, gcb0, g0, B, 64, 16, 16, 8, 8);
    conv3x3<64, 2, true><<<dim3((B*64*4*4 + 255) / 256), 256, 0, stream>>>(
        g0, gcw1, gcb1, g1, B, 64, 8, 8, 4, 4);
    fc_head<<<dim3(B), 256, 0, stream>>>(g1, fcw0, fcb0, fcw1, fcb1, fcw2, fcb2, gvec);

    // fusion + bg 1x1 conv -> reordered grid
    fuse_bg<<<dim3(256, B), 128, 0, stream>>>(loc, gvec, bgw, bgb, grid_r);

    // fused guide + slice + apply
    guide_slice<<<dim3(16, 256, B), 256, 0, stream>>>(
        fr, grid_r, guw0, gub0, guw1, gub1, gd_out, fin_out);
}

// Round 2
// 225.291 us; speedup vs baseline: 1.8462x; 1.8462x over previous
//
#include <hip/hip_runtime.h>
#include <math.h>

#define HW_ (1024*1024)

// ---------------- naive direct 3x3 conv (used only for s0: CIN=3, big grid) ----------------
template<int CIN, int S, bool RELU>
__global__ void conv3x3(const float* __restrict__ in, const float* __restrict__ w,
                        const float* __restrict__ bias, float* __restrict__ out,
                        int B, int COUT, int HIN, int WIN, int HOUT, int WOUT)
{
    int idx = blockIdx.x * blockDim.x + threadIdx.x;
    int total = B * COUT * HOUT * WOUT;
    if (idx >= total) return;
    int wo = idx % WOUT; int t = idx / WOUT;
    int ho = t % HOUT; t /= HOUT;
    int co = t % COUT; int b = t / COUT;

    float acc = bias[co];
    const float* wp = w + co * CIN * 9;
    const float* ip = in + (size_t)b * CIN * HIN * WIN;
    for (int ci = 0; ci < CIN; ci++) {
        #pragma unroll
        for (int kh = 0; kh < 3; kh++) {
            int hi = ho * S - 1 + kh;
            if ((unsigned)hi >= (unsigned)HIN) continue;
            #pragma unroll
            for (int kw = 0; kw < 3; kw++) {
                int wi = wo * S - 1 + kw;
                if ((unsigned)wi >= (unsigned)WIN) continue;
                acc += ip[(ci * HIN + hi) * WIN + wi] * wp[(ci * 3 + kh) * 3 + kw];
            }
        }
    }
    if (RELU) acc = fmaxf(acc, 0.f);
    out[idx] = acc;
}

// -------- 8-way cin-split 3x3 conv: block = 32 pixels x 8 cin-groups, one co per block --------
// grid: (pixel_tiles, COUT, B)
template<int CIN, int S, bool RELU>
__global__ void conv3x3_split(const float* __restrict__ in, const float* __restrict__ w,
                              const float* __restrict__ bias, float* __restrict__ out,
                              int HIN, int WIN, int HOUT, int WOUT)
{
    constexpr int CPT = CIN / 8;               // ci per thread
    __shared__ float wsm[CIN * 9];
    int t = threadIdx.x;                        // 256
    int co = blockIdx.y;
    for (int i = t; i < CIN * 9; i += 256) wsm[i] = w[co * CIN * 9 + i];
    __syncthreads();

    int sub = t & 7;
    int pix = blockIdx.x * 32 + (t >> 3);
    int total_pix = HOUT * WOUT;
    int ho = pix / WOUT, wo = pix % WOUT;
    float acc = 0.f;
    if (pix < total_pix) {
        const float* ip = in + (size_t)blockIdx.z * CIN * HIN * WIN;
        #pragma unroll
        for (int cc = 0; cc < CPT; cc++) {
            int ci = sub * CPT + cc;
            const float* ic = ip + ci * HIN * WIN;
            const float* wr = wsm + ci * 9;
            #pragma unroll
            for (int kh = 0; kh < 3; kh++) {
                int hi = ho * S - 1 + kh;
                if ((unsigned)hi >= (unsigned)HIN) continue;
                #pragma unroll
                for (int kw = 0; kw < 3; kw++) {
                    int wi = wo * S - 1 + kw;
                    if ((unsigned)wi >= (unsigned)WIN) continue;
                    acc += ic[hi * WIN + wi] * wr[kh * 3 + kw];
                }
            }
        }
    }
    acc += __shfl_xor(acc, 1);
    acc += __shfl_xor(acc, 2);
    acc += __shfl_xor(acc, 4);
    if (sub == 0 && pix < total_pix) {
        float r = acc + bias[co];
        if (RELU) r = fmaxf(r, 0.f);
        out[(((size_t)blockIdx.z * gridDim.y + co) * HOUT + ho) * WOUT + wo] = r;
    }
}

// -------- fused gcw1 conv (64->64, 8x8 -> 4x4, s2) + FC head 1024->256->128->64 --------
__global__ void gc1_fc(const float* __restrict__ g0, const float* __restrict__ gcw1,
                       const float* __restrict__ gcb1,
                       const float* __restrict__ w0, const float* __restrict__ b0,
                       const float* __restrict__ w1, const float* __restrict__ b1,
                       const float* __restrict__ w2, const float* __restrict__ b2,
                       float* __restrict__ gvec)
{
    __shared__ float g0s[4096];   // [64][8][8]
    __shared__ float v[1024];
    __shared__ float h0[256];
    __shared__ float h1[128];
    int b = blockIdx.x;
    int t = threadIdx.x;          // 256
    for (int i = t; i < 4096; i += 256) g0s[i] = g0[b * 4096 + i];
    __syncthreads();

    // gcw1 conv: each thread computes 4 outputs sharing pixel (t&15), c = (t>>4)+16*i
    {
        int pix = t & 15; int y = pix >> 2; int x = pix & 3;
        int c0 = t >> 4;
        float acc4[4];
        #pragma unroll
        for (int i = 0; i < 4; i++) acc4[i] = gcb1[c0 + 16 * i];
        const float* wb = gcw1 + c0 * 576;      // + i*16*576 per output
        for (int ci = 0; ci < 64; ci++) {
            #pragma unroll
            for (int kh = 0; kh < 3; kh++) {
                int hi = y * 2 - 1 + kh;
                if ((unsigned)hi >= 8u) continue;
                #pragma unroll
                for (int kw = 0; kw < 3; kw++) {
                    int wi = x * 2 - 1 + kw;
                    if ((unsigned)wi >= 8u) continue;
                    float inv = g0s[(ci * 8 + hi) * 8 + wi];
                    int woff = ci * 9 + kh * 3 + kw;
                    #pragma unroll
                    for (int i = 0; i < 4; i++)
                        acc4[i] += inv * wb[i * 16 * 576 + woff];
                }
            }
        }
        #pragma unroll
        for (int i = 0; i < 4; i++)
            v[(c0 + 16 * i) * 16 + pix] = fmaxf(acc4[i], 0.f);
    }
    __syncthreads();
    {
        float acc = b0[t];
        const float* wr = w0 + t * 1024;
        for (int k = 0; k < 1024; k++) acc += wr[k] * v[k];
        h0[t] = fmaxf(acc, 0.f);
    }
    __syncthreads();
    if (t < 128) {
        float acc = b1[t];
        const float* wr = w1 + t * 256;
        for (int k = 0; k < 256; k++) acc += wr[k] * h0[k];
        h1[t] = fmaxf(acc, 0.f);
    }
    __syncthreads();
    if (t < 64) {
        float acc = b2[t];
        const float* wr = w2 + t * 128;
        for (int k = 0; k < 128; k++) acc += wr[k] * h1[k];
        gvec[b * 64 + t] = acc;
    }
}

// ------- fusion (loc + g broadcast, relu) + 1x1 bg conv -> grid[B,8,16,16,12] -------
__global__ void fuse_bg(const float* __restrict__ loc, const float* __restrict__ gvec,
                        const float* __restrict__ bgw, const float* __restrict__ bgb,
                        float* __restrict__ grid_r)
{
    __shared__ float fused[64];
    int b = blockIdx.y;
    int y = blockIdx.x >> 4, x = blockIdx.x & 15;
    int t = threadIdx.x; // 128 threads
    if (t < 64) {
        fused[t] = fmaxf(loc[((b * 64 + t) * 16 + y) * 16 + x] + gvec[b * 64 + t], 0.f);
    }
    __syncthreads();
    if (t < 96) {
        float acc = bgb[t];
        const float* wr = bgw + t * 64;
        #pragma unroll 8
        for (int k = 0; k < 64; k++) acc += wr[k] * fused[k];
        int c12 = t >> 3, d = t & 7;
        grid_r[((((b * 8 + d) * 16 + y) * 16 + x) * 12) + c12] = acc;
    }
}

// ------- fused guide (1x1 convs + sigmoid) + trilinear slice + affine apply -------
__global__ void guide_slice(const float* __restrict__ fr, const float* __restrict__ grid_r,
                            const float* __restrict__ guw0, const float* __restrict__ gub0,
                            const float* __restrict__ guw1, const float* __restrict__ gub1,
                            float* __restrict__ gd_out, float* __restrict__ fin_out)
{
    const int W = 1024;
    int x = blockIdx.x * 64 + (threadIdx.x & 63);
    int y = blockIdx.y * 4 + (threadIdx.x >> 6);
    int b = blockIdx.z;
    int pix = y * W + x;

    const float* frb = fr + (size_t)b * 3 * HW_;
    float r  = frb[pix];
    float g  = frb[HW_ + pix];
    float bl = frb[2 * HW_ + pix];

    float s = gub1[0];
    #pragma unroll
    for (int c = 0; c < 16; c++) {
        float h = guw0[c * 3] * r + guw0[c * 3 + 1] * g + guw0[c * 3 + 2] * bl + gub0[c];
        h = fmaxf(h, 0.f);
        s += guw1[c] * h;
    }
    float gd = 1.f / (1.f + expf(-s));
    gd_out[(size_t)b * HW_ + pix] = gd;

    float xs = (x + 0.5f) * (1.f / 64.f) - 0.5f;
    float ys = (y + 0.5f) * (1.f / 64.f) - 0.5f;
    float fx = floorf(xs), fy = floorf(ys);
    int x0 = min(max((int)fx, 0), 15); int x1 = min(x0 + 1, 15);
    int y0 = min(max((int)fy, 0), 15); int y1 = min(y0 + 1, 15);
    float wx = xs - fx, wy = ys - fy;

    float gz = gd * 8.f - 0.5f;
    float fz = floorf(gz);
    int z0 = min(max((int)fz, 0), 7); int z1 = min(z0 + 1, 7);
    float wz = gz - fz;

    float acc[12];
    #pragma unroll
    for (int c = 0; c < 12; c++) acc[c] = 0.f;

    const float* gb = grid_r + (size_t)b * 8 * 16 * 16 * 12;
    #pragma unroll
    for (int zi = 0; zi < 2; zi++) {
        int z = zi ? z1 : z0;
        float wzf = zi ? wz : 1.f - wz;
        #pragma unroll
        for (int yi = 0; yi < 2; yi++) {
            int yy = yi ? y1 : y0;
            float wyf = wzf * (yi ? wy : 1.f - wy);
            #pragma unroll
            for (int xi = 0; xi < 2; xi++) {
                int xx = xi ? x1 : x0;
                float wf = wyf * (xi ? wx : 1.f - wx);
                const float4* p = (const float4*)(gb + ((z * 16 + yy) * 16 + xx) * 12);
                float4 a0 = p[0], a1 = p[1], a2 = p[2];
                acc[0] += wf * a0.x; acc[1]  += wf * a0.y; acc[2]  += wf * a0.z; acc[3]  += wf * a0.w;
                acc[4] += wf * a1.x; acc[5]  += wf * a1.y; acc[6]  += wf * a1.z; acc[7]  += wf * a1.w;
                acc[8] += wf * a2.x; acc[9]  += wf * a2.y; acc[10] += wf * a2.z; acc[11] += wf * a2.w;
            }
        }
    }

    float o0 = acc[0] * r + acc[1] * g + acc[2]  * bl + acc[3];
    float o1 = acc[4] * r + acc[5] * g + acc[6]  * bl + acc[7];
    float o2 = acc[8] * r + acc[9] * g + acc[10] * bl + acc[11];
    float* fb = fin_out + (size_t)b * 3 * HW_;
    fb[pix] = o0; fb[HW_ + pix] = o1; fb[2 * HW_ + pix] = o2;
}

extern "C" void kernel_launch(void* const* d_in, const int* in_sizes, int n_in,
                              void* d_out, int out_size, void* d_ws, size_t ws_size,
                              hipStream_t stream) {
    const float* lr   = (const float*)d_in[0];
    const float* fr   = (const float*)d_in[1];
    const float* sw0  = (const float*)d_in[2];  const float* sb0 = (const float*)d_in[3];
    const float* sw1  = (const float*)d_in[4];  const float* sb1 = (const float*)d_in[5];
    const float* sw2  = (const float*)d_in[6];  const float* sb2 = (const float*)d_in[7];
    const float* sw3  = (const float*)d_in[8];  const float* sb3 = (const float*)d_in[9];
    const float* lw0  = (const float*)d_in[10]; const float* lb0 = (const float*)d_in[11];
    const float* lw1  = (const float*)d_in[12]; const float* lb1 = (const float*)d_in[13];
    const float* gcw0 = (const float*)d_in[14]; const float* gcb0 = (const float*)d_in[15];
    const float* gcw1 = (const float*)d_in[16]; const float* gcb1 = (const float*)d_in[17];
    const float* fcw0 = (const float*)d_in[18]; const float* fcb0 = (const float*)d_in[19];
    const float* fcw1 = (const float*)d_in[20]; const float* fcb1 = (const float*)d_in[21];
    const float* fcw2 = (const float*)d_in[22]; const float* fcb2 = (const float*)d_in[23];
    const float* bgw  = (const float*)d_in[24]; const float* bgb = (const float*)d_in[25];
    const float* guw0 = (const float*)d_in[26]; const float* gub0 = (const float*)d_in[27];
    const float* guw1 = (const float*)d_in[28]; const float* gub1 = (const float*)d_in[29];

    float* ws = (float*)d_ws;
    float* ws0    = ws;            // [2,8,128,128]  262144
    float* ws1    = ws + 262144;   // [2,16,64,64]   131072
    float* ws2    = ws + 393216;   // [2,32,32,32]   65536
    float* ws3    = ws + 458752;   // [2,64,16,16]   32768
    float* loc0   = ws + 491520;   // [2,64,16,16]   32768
    float* loc    = ws + 524288;   // [2,64,16,16]   32768
    float* g0     = ws + 557056;   // [2,64,8,8]     8192
    float* gvec   = ws + 567296;   // [2,64]         128
    float* grid_r = ws + 567424;   // [2,8,16,16,12] 49152

    float* gd_out  = (float*)d_out;             // [2,1024,1024]
    float* fin_out = (float*)d_out + 2 * HW_;   // [2,3,1024,1024]

    const int B = 2;

    // s0: 3->8, 256^2 -> 128^2 (naive, plenty of threads)
    conv3x3<3, 2, true><<<dim3((B*8*128*128 + 255) / 256), 256, 0, stream>>>(
        lr, sw0, sb0, ws0, B, 8, 256, 256, 128, 128);
    // s1: 8->16, 128^2 -> 64^2
    conv3x3_split<8, 2, true><<<dim3(128, 16, B), 256, 0, stream>>>(
        ws0, sw1, sb1, ws1, 128, 128, 64, 64);
    // s2: 16->32, 64^2 -> 32^2
    conv3x3_split<16, 2, true><<<dim3(32, 32, B), 256, 0, stream>>>(
        ws1, sw2, sb2, ws2, 64, 64, 32, 32);
    // s3: 32->64, 32^2 -> 16^2
    conv3x3_split<32, 2, true><<<dim3(8, 64, B), 256, 0, stream>>>(
        ws2, sw3, sb3, ws3, 32, 32, 16, 16);

    // local path: two 64->64 @16x16
    conv3x3_split<64, 1, true><<<dim3(8, 64, B), 256, 0, stream>>>(
        ws3, lw0, lb0, loc0, 16, 16, 16, 16);
    conv3x3_split<64, 1, false><<<dim3(8, 64, B), 256, 0, stream>>>(
        loc0, lw1, lb1, loc, 16, 16, 16, 16);

    // global path: gcw0 64->64 @16->8, then fused gcw1+FC
    conv3x3_split<64, 2, true><<<dim3(2, 64, B), 256, 0, stream>>>(
        ws3, gcw0, gcb0, g0, 16, 16, 8, 8);
    gc1_fc<<<dim3(B), 256, 0, stream>>>(g0, gcw1, gcb1,
        fcw0, fcb0, fcw1, fcb1, fcw2, fcb2, gvec);

    // fusion + bg 1x1 conv -> reordered grid
    fuse_bg<<<dim3(256, B), 128, 0, stream>>>(loc, gvec, bgw, bgb, grid_r);

    // fused guide + slice + apply
    guide_slice<<<dim3(16, 256, B), 256, 0, stream>>>(
        fr, grid_r, guw0, gub0, guw1, gub1, gd_out, fin_out);
}

// Round 3
// 149.443 us; speedup vs baseline: 2.7833x; 1.5075x over previous
//
#include <hip/hip_runtime.h>
#include <math.h>

#define HW_ (1024*1024)

// ---------------- naive direct 3x3 conv (used only for s0: CIN=3, big grid) ----------------
template<int CIN, int S, bool RELU>
__global__ void conv3x3(const float* __restrict__ in, const float* __restrict__ w,
                        const float* __restrict__ bias, float* __restrict__ out,
                        int B, int COUT, int HIN, int WIN, int HOUT, int WOUT)
{
    int idx = blockIdx.x * blockDim.x + threadIdx.x;
    int total = B * COUT * HOUT * WOUT;
    if (idx >= total) return;
    int wo = idx % WOUT; int t = idx / WOUT;
    int ho = t % HOUT; t /= HOUT;
    int co = t % COUT; int b = t / COUT;

    float acc = bias[co];
    const float* wp = w + co * CIN * 9;
    const float* ip = in + (size_t)b * CIN * HIN * WIN;
    for (int ci = 0; ci < CIN; ci++) {
        #pragma unroll
        for (int kh = 0; kh < 3; kh++) {
            int hi = ho * S - 1 + kh;
            if ((unsigned)hi >= (unsigned)HIN) continue;
            #pragma unroll
            for (int kw = 0; kw < 3; kw++) {
                int wi = wo * S - 1 + kw;
                if ((unsigned)wi >= (unsigned)WIN) continue;
                acc += ip[(ci * HIN + hi) * WIN + wi] * wp[(ci * 3 + kh) * 3 + kw];
            }
        }
    }
    if (RELU) acc = fmaxf(acc, 0.f);
    out[idx] = acc;
}

// -------- 8-way cin-split 3x3 conv: block = 32 pixels x 8 cin-groups, one co per block --------
// grid: (pixel_tiles, COUT, B)
template<int CIN, int S, bool RELU>
__global__ void conv3x3_split(const float* __restrict__ in, const float* __restrict__ w,
                              const float* __restrict__ bias, float* __restrict__ out,
                              int HIN, int WIN, int HOUT, int WOUT)
{
    constexpr int CPT = CIN / 8;               // ci per thread
    __shared__ float wsm[CIN * 9];
    int t = threadIdx.x;                        // 256
    int co = blockIdx.y;
    for (int i = t; i < CIN * 9; i += 256) wsm[i] = w[co * CIN * 9 + i];
    __syncthreads();

    int sub = t & 7;
    int pix = blockIdx.x * 32 + (t >> 3);
    int total_pix = HOUT * WOUT;
    int ho = pix / WOUT, wo = pix % WOUT;
    float acc = 0.f;
    if (pix < total_pix) {
        const float* ip = in + (size_t)blockIdx.z * CIN * HIN * WIN;
        #pragma unroll
        for (int cc = 0; cc < CPT; cc++) {
            int ci = sub * CPT + cc;
            const float* ic = ip + ci * HIN * WIN;
            const float* wr = wsm + ci * 9;
            #pragma unroll
            for (int kh = 0; kh < 3; kh++) {
                int hi = ho * S - 1 + kh;
                if ((unsigned)hi >= (unsigned)HIN) continue;
                #pragma unroll
                for (int kw = 0; kw < 3; kw++) {
                    int wi = wo * S - 1 + kw;
                    if ((unsigned)wi >= (unsigned)WIN) continue;
                    acc += ic[hi * WIN + wi] * wr[kh * 3 + kw];
                }
            }
        }
    }
    acc += __shfl_xor(acc, 1);
    acc += __shfl_xor(acc, 2);
    acc += __shfl_xor(acc, 4);
    if (sub == 0 && pix < total_pix) {
        float r = acc + bias[co];
        if (RELU) r = fmaxf(r, 0.f);
        out[(((size_t)blockIdx.z * gridDim.y + co) * HOUT + ho) * WOUT + wo] = r;
    }
}

// -------- wave-per-output GEMV: out[b,o] = act(w[o,:] . in[b,:] + bias[o]) --------
// NIN elements per row, divisible by 64*ELT (ELT floats per lane). OPB = outputs total per batch.
template<int NIN, int OPB, bool RELU>
__global__ void fc_gemv(const float* __restrict__ in, const float* __restrict__ w,
                        const float* __restrict__ bias, float* __restrict__ out)
{
    int gw = (blockIdx.x * blockDim.x + threadIdx.x) >> 6;  // global wave id
    int lane = threadIdx.x & 63;
    int b = gw / OPB, o = gw % OPB;

    constexpr int NIT = NIN / 256;   // float4 iterations (NIN multiple of 256)
    const float4* wr = (const float4*)(w + o * NIN);
    const float4* vr = (const float4*)(in + b * NIN);
    float acc = 0.f;
    #pragma unroll
    for (int i = 0; i < NIT; i++) {
        float4 a = wr[i * 64 + lane];
        float4 x = vr[i * 64 + lane];
        acc += a.x * x.x + a.y * x.y + a.z * x.z + a.w * x.w;
    }
    acc += __shfl_xor(acc, 1);
    acc += __shfl_xor(acc, 2);
    acc += __shfl_xor(acc, 4);
    acc += __shfl_xor(acc, 8);
    acc += __shfl_xor(acc, 16);
    acc += __shfl_xor(acc, 32);
    if (lane == 0) {
        float r = acc + bias[o];
        if (RELU) r = fmaxf(r, 0.f);
        out[b * OPB + o] = r;
    }
}

// FC2: 128 inputs (float2 per lane)
__global__ void fc_gemv128(const float* __restrict__ in, const float* __restrict__ w,
                           const float* __restrict__ bias, float* __restrict__ out)
{
    int gw = (blockIdx.x * blockDim.x + threadIdx.x) >> 6;
    int lane = threadIdx.x & 63;
    int b = gw >> 6, o = gw & 63;
    const float2* wr = (const float2*)(w + o * 128);
    const float2* vr = (const float2*)(in + b * 128);
    float2 a = wr[lane], x = vr[lane];
    float acc = a.x * x.x + a.y * x.y;
    acc += __shfl_xor(acc, 1);
    acc += __shfl_xor(acc, 2);
    acc += __shfl_xor(acc, 4);
    acc += __shfl_xor(acc, 8);
    acc += __shfl_xor(acc, 16);
    acc += __shfl_xor(acc, 32);
    if (lane == 0) out[b * 64 + o] = acc + bias[o];
}

// ------- fusion (loc + g broadcast, relu) + 1x1 bg conv -> grid[B,8,16,16,12] -------
__global__ void fuse_bg(const float* __restrict__ loc, const float* __restrict__ gvec,
                        const float* __restrict__ bgw, const float* __restrict__ bgb,
                        float* __restrict__ grid_r)
{
    __shared__ float fused[64];
    int b = blockIdx.y;
    int y = blockIdx.x >> 4, x = blockIdx.x & 15;
    int t = threadIdx.x; // 128 threads
    if (t < 64) {
        fused[t] = fmaxf(loc[((b * 64 + t) * 16 + y) * 16 + x] + gvec[b * 64 + t], 0.f);
    }
    __syncthreads();
    if (t < 96) {
        float acc = bgb[t];
        const float* wr = bgw + t * 64;
        #pragma unroll 8
        for (int k = 0; k < 64; k++) acc += wr[k] * fused[k];
        int c12 = t >> 3, d = t & 7;
        grid_r[((((b * 8 + d) * 16 + y) * 16 + x) * 12) + c12] = acc;
    }
}

// ------- fused guide (1x1 convs + sigmoid) + trilinear slice + affine apply -------
__global__ void guide_slice(const float* __restrict__ fr, const float* __restrict__ grid_r,
                            const float* __restrict__ guw0, const float* __restrict__ gub0,
                            const float* __restrict__ guw1, const float* __restrict__ gub1,
                            float* __restrict__ gd_out, float* __restrict__ fin_out)
{
    const int W = 1024;
    int x = blockIdx.x * 64 + (threadIdx.x & 63);
    int y = blockIdx.y * 4 + (threadIdx.x >> 6);
    int b = blockIdx.z;
    int pix = y * W + x;

    const float* frb = fr + (size_t)b * 3 * HW_;
    float r  = frb[pix];
    float g  = frb[HW_ + pix];
    float bl = frb[2 * HW_ + pix];

    float s = gub1[0];
    #pragma unroll
    for (int c = 0; c < 16; c++) {
        float h = guw0[c * 3] * r + guw0[c * 3 + 1] * g + guw0[c * 3 + 2] * bl + gub0[c];
        h = fmaxf(h, 0.f);
        s += guw1[c] * h;
    }
    float gd = 1.f / (1.f + expf(-s));
    gd_out[(size_t)b * HW_ + pix] = gd;

    float xs = (x + 0.5f) * (1.f / 64.f) - 0.5f;
    float ys = (y + 0.5f) * (1.f / 64.f) - 0.5f;
    float fx = floorf(xs), fy = floorf(ys);
    int x0 = min(max((int)fx, 0), 15); int x1 = min(x0 + 1, 15);
    int y0 = min(max((int)fy, 0), 15); int y1 = min(y0 + 1, 15);
    float wx = xs - fx, wy = ys - fy;

    float gz = gd * 8.f - 0.5f;
    float fz = floorf(gz);
    int z0 = min(max((int)fz, 0), 7); int z1 = min(z0 + 1, 7);
    float wz = gz - fz;

    float acc[12];
    #pragma unroll
    for (int c = 0; c < 12; c++) acc[c] = 0.f;

    const float* gb = grid_r + (size_t)b * 8 * 16 * 16 * 12;
    #pragma unroll
    for (int zi = 0; zi < 2; zi++) {
        int z = zi ? z1 : z0;
        float wzf = zi ? wz : 1.f - wz;
        #pragma unroll
        for (int yi = 0; yi < 2; yi++) {
            int yy = yi ? y1 : y0;
            float wyf = wzf * (yi ? wy : 1.f - wy);
            #pragma unroll
            for (int xi = 0; xi < 2; xi++) {
                int xx = xi ? x1 : x0;
                float wf = wyf * (xi ? wx : 1.f - wx);
                const float4* p = (const float4*)(gb + ((z * 16 + yy) * 16 + xx) * 12);
                float4 a0 = p[0], a1 = p[1], a2 = p[2];
                acc[0] += wf * a0.x; acc[1]  += wf * a0.y; acc[2]  += wf * a0.z; acc[3]  += wf * a0.w;
                acc[4] += wf * a1.x; acc[5]  += wf * a1.y; acc[6]  += wf * a1.z; acc[7]  += wf * a1.w;
                acc[8] += wf * a2.x; acc[9]  += wf * a2.y; acc[10] += wf * a2.z; acc[11] += wf * a2.w;
            }
        }
    }

    float o0 = acc[0] * r + acc[1] * g + acc[2]  * bl + acc[3];
    float o1 = acc[4] * r + acc[5] * g + acc[6]  * bl + acc[7];
    float o2 = acc[8] * r + acc[9] * g + acc[10] * bl + acc[11];
    float* fb = fin_out + (size_t)b * 3 * HW_;
    fb[pix] = o0; fb[HW_ + pix] = o1; fb[2 * HW_ + pix] = o2;
}

extern "C" void kernel_launch(void* const* d_in, const int* in_sizes, int n_in,
                              void* d_out, int out_size, void* d_ws, size_t ws_size,
                              hipStream_t stream) {
    const float* lr   = (const float*)d_in[0];
    const float* fr   = (const float*)d_in[1];
    const float* sw0  = (const float*)d_in[2];  const float* sb0 = (const float*)d_in[3];
    const float* sw1  = (const float*)d_in[4];  const float* sb1 = (const float*)d_in[5];
    const float* sw2  = (const float*)d_in[6];  const float* sb2 = (const float*)d_in[7];
    const float* sw3  = (const float*)d_in[8];  const float* sb3 = (const float*)d_in[9];
    const float* lw0  = (const float*)d_in[10]; const float* lb0 = (const float*)d_in[11];
    const float* lw1  = (const float*)d_in[12]; const float* lb1 = (const float*)d_in[13];
    const float* gcw0 = (const float*)d_in[14]; const float* gcb0 = (const float*)d_in[15];
    const float* gcw1 = (const float*)d_in[16]; const float* gcb1 = (const float*)d_in[17];
    const float* fcw0 = (const float*)d_in[18]; const float* fcb0 = (const float*)d_in[19];
    const float* fcw1 = (const float*)d_in[20]; const float* fcb1 = (const float*)d_in[21];
    const float* fcw2 = (const float*)d_in[22]; const float* fcb2 = (const float*)d_in[23];
    const float* bgw  = (const float*)d_in[24]; const float* bgb = (const float*)d_in[25];
    const float* guw0 = (const float*)d_in[26]; const float* gub0 = (const float*)d_in[27];
    const float* guw1 = (const float*)d_in[28]; const float* gub1 = (const float*)d_in[29];

    float* ws = (float*)d_ws;
    float* ws0    = ws;            // [2,8,128,128]  262144
    float* ws1    = ws + 262144;   // [2,16,64,64]   131072
    float* ws2    = ws + 393216;   // [2,32,32,32]   65536
    float* ws3    = ws + 458752;   // [2,64,16,16]   32768
    float* loc0   = ws + 491520;   // [2,64,16,16]   32768
    float* loc    = ws + 524288;   // [2,64,16,16]   32768
    float* g0     = ws + 557056;   // [2,64,8,8]     8192
    float* v      = ws + 565248;   // [2,1024]       2048
    float* h0     = ws + 567296;   // [2,256]        512
    float* h1     = ws + 567808;   // [2,128]        256
    float* gvec   = ws + 568064;   // [2,64]         128
    float* grid_r = ws + 568192;   // [2,8,16,16,12] 49152

    float* gd_out  = (float*)d_out;             // [2,1024,1024]
    float* fin_out = (float*)d_out + 2 * HW_;   // [2,3,1024,1024]

    const int B = 2;

    // s0: 3->8, 256^2 -> 128^2 (naive, plenty of threads)
    conv3x3<3, 2, true><<<dim3((B*8*128*128 + 255) / 256), 256, 0, stream>>>(
        lr, sw0, sb0, ws0, B, 8, 256, 256, 128, 128);
    // s1: 8->16, 128^2 -> 64^2
    conv3x3_split<8, 2, true><<<dim3(128, 16, B), 256, 0, stream>>>(
        ws0, sw1, sb1, ws1, 128, 128, 64, 64);
    // s2: 16->32, 64^2 -> 32^2
    conv3x3_split<16, 2, true><<<dim3(32, 32, B), 256, 0, stream>>>(
        ws1, sw2, sb2, ws2, 64, 64, 32, 32);
    // s3: 32->64, 32^2 -> 16^2
    conv3x3_split<32, 2, true><<<dim3(8, 64, B), 256, 0, stream>>>(
        ws2, sw3, sb3, ws3, 32, 32, 16, 16);

    // local path: two 64->64 @16x16
    conv3x3_split<64, 1, true><<<dim3(8, 64, B), 256, 0, stream>>>(
        ws3, lw0, lb0, loc0, 16, 16, 16, 16);
    conv3x3_split<64, 1, false><<<dim3(8, 64, B), 256, 0, stream>>>(
        loc0, lw1, lb1, loc, 16, 16, 16, 16);

    // global path: gcw0 64->64 @16->8
    conv3x3_split<64, 2, true><<<dim3(2, 64, B), 256, 0, stream>>>(
        ws3, gcw0, gcb0, g0, 16, 16, 8, 8);
    // gcw1 64->64 @8->4, output in [b][c*16+y*4+x] order == flattened v[B,1024]
    conv3x3_split<64, 2, true><<<dim3(1, 64, B), 256, 0, stream>>>(
        g0, gcw1, gcb1, v, 8, 8, 4, 4);

    // FC head, wave-per-output GEMVs
    fc_gemv<1024, 256, true><<<dim3(B * 256 / 4), 256, 0, stream>>>(v, fcw0, fcb0, h0);
    fc_gemv<256, 128, true><<<dim3(B * 128 / 4), 256, 0, stream>>>(h0, fcw1, fcb1, h1);
    fc_gemv128<<<dim3(B * 64 / 4), 256, 0, stream>>>(h1, fcw2, fcb2, gvec);

    // fusion + bg 1x1 conv -> reordered grid
    fuse_bg<<<dim3(256, B), 128, 0, stream>>>(loc, gvec, bgw, bgb, grid_r);

    // fused guide + slice + apply
    guide_slice<<<dim3(16, 256, B), 256, 0, stream>>>(
        fr, grid_r, guw0, gub0, guw1, gub1, gd_out, fin_out);
}